// Round 7
// baseline (16198.767 us; speedup 1.0000x reference)
//
#include <hip/hip_runtime.h>
#include <cmath>

// ---------------- problem constants ----------------
#define HID    896
#define HALFD  448
#define BB     16
#define SS     2048
#define NWG    28         // 28 WGs x 32 hidden dims each (launch exactly 28)

#define SENT32 0x7F7F7F7Fu
#define SENT64 0x7F7F7F7F7F7F7F7FULL   // f16 0x7F7F = NaN; |h|<=1 never produces it

typedef _Float16 half8  __attribute__((ext_vector_type(8)));
typedef float    f32x4v __attribute__((ext_vector_type(4)));
typedef unsigned uint4v __attribute__((ext_vector_type(4)));

static __device__ __forceinline__ f32x4v mfma16(half8 a, half8 b, f32x4v c) {
    return __builtin_amdgcn_mfma_f32_16x16x32_f16(a, b, c, 0, 0, 0);
}

// Device-coherent 16B load (bypass L1+L2, read at MALL) — exact R2-proven
// instruction, upgraded to "=&v" so the dest can never alias the address
// pair (the pointer lives across poll-loop iterations).
static __device__ __forceinline__ half8 ld_h(const _Float16* p) {
    half8 r;
    asm volatile("global_load_dwordx4 %0, %1, off sc0 sc1" : "=&v"(r) : "v"(p));
    return r;
}

// ---------------- workspace layout (bytes) ----------------
#define OFF_WHH16 0UL          // W_hh f16 [2688][896]
#define OFF_WC1T  4816896UL    // head weights, transposed f16
#define OFF_WF1T  5218304UL
#define OFF_WC2T  5619712UL
#define OFF_WF2T  5849088UL
#define OFF_HBUF  6078464UL    // h TRIPLE buffer f16 [3][16][896] (86016 B)
#define OFF_HC    6164480UL    // hidden_coarse f16 [32768][448]
// end: 35,524,608

// ============================================================
// Kernel 1: convert weights fp32 -> f16 (unchanged from R2)
// ============================================================
__global__ void wrnn_conv(const float* __restrict__ Whh,
                          const float* __restrict__ Wc1, const float* __restrict__ Wc2,
                          const float* __restrict__ Wf1, const float* __restrict__ Wf2,
                          _Float16* __restrict__ Whh16,
                          _Float16* __restrict__ Wc1T, _Float16* __restrict__ Wc2T,
                          _Float16* __restrict__ Wf1T, _Float16* __restrict__ Wf2T)
{
    const int tid    = blockIdx.x * blockDim.x + threadIdx.x;
    const int stride = gridDim.x * blockDim.x;
    for (int i = tid; i < 2688 * 896; i += stride) Whh16[i] = (_Float16)Whh[i];
    for (int i = tid; i < 448 * 448; i += stride) {
        int n = i / 448, k = i % 448;
        Wc1T[i] = (_Float16)Wc1[k * 448 + n];
        Wf1T[i] = (_Float16)Wf1[k * 448 + n];
    }
    for (int i = tid; i < 256 * 448; i += stride) {
        int n = i / 448, k = i % 448;
        Wc2T[i] = (_Float16)Wc2[k * 256 + n];
        Wf2T[i] = (_Float16)Wf2[k * 256 + n];
    }
}

// ============================================================
// Kernel 2: fused projections + GRU scan — flag-free sentinel protocol.
// 28 WGs x 192 thr (R2 structure). WG w owns dims [32w,32w+32); wave g owns
// gate g; A pinned in VGPRs. 3 rotating h buffers (sentinel 0x7F7F):
//   step t: poll-read h(t) from buf[t%3] until no 8B granule is sentinel;
//           wave0 refills buf[(t+2)%3] with sentinel (safe: any consumer of
//           that buffer at t+2 is gated on h(t+1), published after the fill);
//           one __syncthreads; wave0 combines + publishes h(t+1) -> buf[(t+1)%3]
//           (no flags, no post-publish drain — consumers poll the data itself).
// Cross-WG primitives = exact R2-proven pairing (sc0 sc1 loads / AGENT
// atomic stores). Gate LDS double-buffered by t&1 (single barrier per step).
// ============================================================
__global__ __launch_bounds__(192, 1) void wrnn_scan(
    const float* __restrict__ cond,   // [16][2048][3][896]
    const float* __restrict__ sig,    // [16][2048][2]
    const float* __restrict__ tcg,    // [16][2048]
    const float* __restrict__ Wc,     // [2][1344]
    const float* __restrict__ Wf,     // [3][1344]
    const float* __restrict__ bih,    // [2688]
    const float* __restrict__ bhh,    // [2688]
    const _Float16* __restrict__ Whh16, // [2688][896]
    _Float16* __restrict__ hbuf,      // [3][16][896]
    _Float16* __restrict__ hc)        // [32768][448]
{
    const int w  = blockIdx.x;
    const int g  = threadIdx.x >> 6;  // gate = wave (0:r 1:z 2:n)
    const int l  = threadIdx.x & 63;
    const int b  = l & 15;            // batch (MFMA col)
    const int lg = l >> 4;
    const int dbase = w * 32;
    const bool hw = (dbase < HALFD);

    // ---- persistent A fragments: W_hh rows [g*896+dbase .. +32), all K ----
    half8 A0[28], A1[28];
    {
        const _Float16* ap = Whh16 + (size_t)(g * HID + dbase + b) * HID + lg * 8;
        #pragma unroll
        for (int f = 0; f < 28; ++f) {
            A0[f] = *(const half8*)(ap + f * 32);
            A1[f] = *(const half8*)(ap + (size_t)16 * HID + f * 32);
        }
    }

    // ---- per-lane constants for the 8 owned outputs ----
    float pc0[8], pc1[8], pc2[8], bi8[8], bh8[8];
    #pragma unroll
    for (int e = 0; e < 8; ++e) {
        int i = dbase + (e >> 2) * 16 + lg * 4 + (e & 3);
        int j = g * HID + i;
        bi8[e] = bih[j]; bh8[e] = bhh[j];
        if (i < HALFD) { int col = g * HALFD + i;
            pc0[e] = Wc[col]; pc1[e] = Wc[1344 + col]; pc2[e] = 0.f; }
        else { int col = g * HALFD + (i - HALFD);
            pc0[e] = Wf[col]; pc1[e] = Wf[1344 + col]; pc2[e] = Wf[2688 + col]; }
    }

    __shared__ float lds_z[2][512], lds_nm[2][512], lds_xn[2][512];
    const int x0 = lg * 64 + b;       // + (e&3)*16 + (e>>2)*256

    const float* cb  = cond + ((size_t)b * SS * 3 + g) * HID + dbase + lg * 4;
    const float* sp  = sig + (size_t)b * SS * 2;
    const float* tp  = tcg + (size_t)b * SS;
    _Float16* hcp = hc + (size_t)b * SS * HALFD + dbase + lg * 4;

    float hold[8] = {0,0,0,0,0,0,0,0};
    float r8[8];

    int rb0 = 0, rb1 = 1, rb2 = 2;    // poll / publish / sentinel-fill buffers

    for (int t = 0; t < SS; ++t) {
        // pin A fragments in VGPRs (defeat reload/remat)
        #pragma unroll
        for (int f = 0; f < 28; ++f) {
            asm volatile("" : "+v"(A0[f]));
            asm volatile("" : "+v"(A1[f]));
        }

        // ---- poll-read h(t) from buf[rb0] (all waves; self-synchronizing) ----
        half8 Bf[28];
        if (t > 0) {
            const _Float16* hb = hbuf + (size_t)rb0 * (BB * HID)
                                      + (size_t)b * HID + lg * 8;
            while (true) {
                #pragma unroll
                for (int f = 0; f < 28; ++f) Bf[f] = ld_h(hb + f * 32);
                asm volatile("s_waitcnt vmcnt(0)" ::: "memory");
                __builtin_amdgcn_sched_barrier(0);
                int bad = 0;
                #pragma unroll
                for (int f = 0; f < 28; ++f) {
                    uint4v u = __builtin_bit_cast(uint4v, Bf[f]);
                    bad |= (u[0] == SENT32) ? 1 : 0;   // granule 0 (8B store)
                    bad |= (u[2] == SENT32) ? 1 : 0;   // granule 1 (8B store)
                }
                if (!__any(bad)) break;
                __builtin_amdgcn_s_sleep(1);
            }
        }

        // ---- wave0: sentinel-refill own slice of buf[rb2] (issue now; the
        // drain happens post-combine so it overlaps MFMA/gates) ----
        if (g == 0) {
            _Float16* fb = hbuf + (size_t)rb2 * (BB * HID)
                                + (size_t)b * HID + dbase + lg * 4;
            __hip_atomic_store((unsigned long long*)fb,        SENT64,
                               __ATOMIC_RELAXED, __HIP_MEMORY_SCOPE_AGENT);
            __hip_atomic_store((unsigned long long*)(fb + 16), SENT64,
                               __ATOMIC_RELAXED, __HIP_MEMORY_SCOPE_AGENT);
        }

        // ---- h-independent inputs (plain cached loads) ----
        f32x4v cv0 = *(const f32x4v*)cb;
        f32x4v cv1 = *(const f32x4v*)(cb + 16);
        float s0 = sp[2 * t], s1 = sp[2 * t + 1], tc = tp[t];

        // ---- y = W_slice @ h(t) ----
        f32x4v acc0 = {0,0,0,0}, acc1 = {0,0,0,0}, acc2 = {0,0,0,0}, acc3 = {0,0,0,0};
        if (t > 0) {
            #pragma unroll
            for (int f = 0; f < 28; f += 2) {
                acc0 = mfma16(A0[f],     Bf[f],     acc0);
                acc1 = mfma16(A1[f],     Bf[f],     acc1);
                acc2 = mfma16(A0[f + 1], Bf[f + 1], acc2);
                acc3 = mfma16(A1[f + 1], Bf[f + 1], acc3);
            }
        }
        f32x4v accA = acc0 + acc2, accB = acc1 + acc3;
        float accv[8] = {accA[0],accA[1],accA[2],accA[3],
                         accB[0],accB[1],accB[2],accB[3]};
        float cvv[8]  = {cv0[0],cv0[1],cv0[2],cv0[3],
                         cv1[0],cv1[1],cv1[2],cv1[3]};

        // ---- gate pre-activations into LDS[t&1] ----
        const int sl = t & 1;
        if (g == 0) {
            #pragma unroll
            for (int e = 0; e < 8; ++e) {
                float pre = accv[e] + cvv[e] + pc0[e]*s0 + pc1[e]*s1
                          + pc2[e]*tc + bi8[e] + bh8[e];
                r8[e] = 1.f / (1.f + expf(-pre));
            }
        } else if (g == 1) {
            #pragma unroll
            for (int e = 0; e < 8; ++e) {
                float pre = accv[e] + cvv[e] + pc0[e]*s0 + pc1[e]*s1
                          + pc2[e]*tc + bi8[e] + bh8[e];
                lds_z[sl][(e >> 2) * 256 + x0 + (e & 3) * 16] = 1.f / (1.f + expf(-pre));
            }
        } else {
            #pragma unroll
            for (int e = 0; e < 8; ++e) {
                lds_nm[sl][(e >> 2) * 256 + x0 + (e & 3) * 16] = accv[e] + bh8[e];
                lds_xn[sl][(e >> 2) * 256 + x0 + (e & 3) * 16] =
                    cvv[e] + pc0[e]*s0 + pc1[e]*s1 + pc2[e]*tc + bi8[e];
            }
        }
        __syncthreads();   // the ONLY per-step barrier (gate LDS is t&1-dbuf'd)

        // ---- wave0: combine, publish h(t+1) into buf[rb1] ----
        if (g == 0) {
            union { _Float16 h[4]; unsigned long long u; } q0, q1;
            #pragma unroll
            for (int e = 0; e < 8; ++e) {
                int idx = (e >> 2) * 256 + x0 + (e & 3) * 16;
                float z  = lds_z[sl][idx];
                float nn = tanhf(lds_xn[sl][idx] + r8[e] * lds_nm[sl][idx]);
                float h  = (1.f - z) * nn + z * hold[e];
                hold[e] = h;
                if (e < 4) q0.h[e] = (_Float16)h; else q1.h[e - 4] = (_Float16)h;
            }
            // drain the sentinel-fill BEFORE publishing (visibility order:
            // fill(t) must never be seen after h(t+1)); overlapped with the
            // MFMA/gate phase above, so this wait is usually free.
            asm volatile("s_waitcnt vmcnt(0)" ::: "memory");
            _Float16* pb = hbuf + (size_t)rb1 * (BB * HID)
                                + (size_t)b * HID + dbase + lg * 4;
            __hip_atomic_store((unsigned long long*)pb,        q0.u,
                               __ATOMIC_RELAXED, __HIP_MEMORY_SCOPE_AGENT);
            __hip_atomic_store((unsigned long long*)(pb + 16), q1.u,
                               __ATOMIC_RELAXED, __HIP_MEMORY_SCOPE_AGENT);
            if (hw) {      // hidden_coarse row t = h(t+1) (plain HBM stores)
                *(unsigned long long*)(hcp)      = q0.u;
                *(unsigned long long*)(hcp + 16) = q1.u;
            }
        }

        // rotate buffers: poll<-publish, publish<-fill, fill<-old poll
        int tmp = rb0; rb0 = rb1; rb1 = rb2; rb2 = tmp;
        cb += 3 * HID; hcp += HALFD;
    }
}

// ============================================================
// Kernel 3: output heads. grid 1024 = 512 row-tiles x 2 paths. (unchanged)
// ============================================================
__global__ __launch_bounds__(256, 2) void wrnn_head(
    const _Float16* __restrict__ hc,
    const _Float16* __restrict__ W1Tc, const _Float16* __restrict__ W1Tf,
    const _Float16* __restrict__ W2Tc, const _Float16* __restrict__ W2Tf,
    const float* __restrict__ b1c, const float* __restrict__ b1f,
    const float* __restrict__ b2c, const float* __restrict__ b2f,
    float* __restrict__ out)
{
    const int path = blockIdx.x & 1;
    const int rt   = blockIdx.x >> 1;
    const int wm   = threadIdx.x >> 6;
    const int l    = threadIdx.x & 63;
    const int ln   = l & 15, lg = l >> 4;
    const int rowbase = rt * 64;

    const _Float16* W1T = path ? W1Tf : W1Tc;
    const _Float16* W2T = path ? W2Tf : W2Tc;
    const float* b1 = path ? b1f : b1c;
    const float* b2 = path ? b2f : b2c;

    __shared__ _Float16 T[64 * 456];

    f32x4v acc[28];
    #pragma unroll
    for (int nt = 0; nt < 28; ++nt) acc[nt] = f32x4v{0,0,0,0};
    const _Float16* ab = hc + (size_t)(rowbase + wm * 16 + ln) * HALFD + lg * 8;
    for (int f = 0; f < 14; ++f) {
        half8 a = *(const half8*)(ab + f * 32);
        #pragma unroll
        for (int nt = 0; nt < 28; ++nt) {
            half8 bb = *(const half8*)(W1T + (size_t)(nt * 16 + ln) * HALFD + f * 32 + lg * 8);
            acc[nt] = mfma16(a, bb, acc[nt]);
        }
    }
    #pragma unroll
    for (int nt = 0; nt < 28; ++nt) {
        float bias = b1[nt * 16 + ln];
        #pragma unroll
        for (int q = 0; q < 4; ++q) {
            float v = fmaxf(acc[nt][q] + bias, 0.f);
            T[(wm * 16 + lg * 4 + q) * 456 + nt * 16 + ln] = (_Float16)v;
        }
    }
    __syncthreads();

    f32x4v a2[16];
    #pragma unroll
    for (int nt = 0; nt < 16; ++nt) a2[nt] = f32x4v{0,0,0,0};
    for (int f = 0; f < 14; ++f) {
        half8 a = *(const half8*)(&T[(wm * 16 + ln) * 456 + f * 32 + lg * 8]);
        #pragma unroll
        for (int nt = 0; nt < 16; ++nt) {
            half8 bb = *(const half8*)(W2T + (size_t)(nt * 16 + ln) * HALFD + f * 32 + lg * 8);
            a2[nt] = mfma16(a, bb, a2[nt]);
        }
    }
    #pragma unroll
    for (int nt = 0; nt < 16; ++nt) {
        float bias = b2[nt * 16 + ln];
        #pragma unroll
        for (int q = 0; q < 4; ++q) {
            size_t row = (size_t)rowbase + wm * 16 + lg * 4 + q;
            out[(size_t)path * (32768UL * 256UL) + row * 256 + nt * 16 + ln] = a2[nt][q] + bias;
        }
    }
}

// ============================================================
extern "C" void kernel_launch(void* const* d_in, const int* in_sizes, int n_in,
                              void* d_out, int out_size, void* d_ws, size_t ws_size,
                              hipStream_t stream)
{
    (void)in_sizes; (void)n_in; (void)out_size; (void)ws_size;
    const float* cond = (const float*)d_in[0];
    const float* sig  = (const float*)d_in[1];
    const float* tcg  = (const float*)d_in[2];
    const float* Wc   = (const float*)d_in[3];
    const float* Wf   = (const float*)d_in[4];
    const float* Whh  = (const float*)d_in[5];
    const float* bih  = (const float*)d_in[6];
    const float* bhh  = (const float*)d_in[7];
    const float* Wc1  = (const float*)d_in[8];
    const float* bc1  = (const float*)d_in[9];
    const float* Wc2  = (const float*)d_in[10];
    const float* bc2  = (const float*)d_in[11];
    const float* Wf1  = (const float*)d_in[12];
    const float* bf1  = (const float*)d_in[13];
    const float* Wf2  = (const float*)d_in[14];
    const float* bf2  = (const float*)d_in[15];

    char* ws = (char*)d_ws;
    _Float16* Whh16 = (_Float16*)(ws + OFF_WHH16);
    _Float16* Wc1T  = (_Float16*)(ws + OFF_WC1T);
    _Float16* Wf1T  = (_Float16*)(ws + OFF_WF1T);
    _Float16* Wc2T  = (_Float16*)(ws + OFF_WC2T);
    _Float16* Wf2T  = (_Float16*)(ws + OFF_WF2T);
    _Float16* hbuf  = (_Float16*)(ws + OFF_HBUF);
    _Float16* hc    = (_Float16*)(ws + OFF_HC);

    // sentinel-initialize ALL THREE h buffers (byte 0x7F -> f16 NaN pattern);
    // stream-ordered before the scan, captured in the graph each replay.
    hipMemsetAsync(hbuf, 0x7F, 3 * BB * HID * sizeof(_Float16), stream);

    wrnn_conv<<<1024, 256, 0, stream>>>(Whh, Wc1, Wc2, Wf1, Wf2,
                                        Whh16, Wc1T, Wc2T, Wf1T, Wf2T);

    wrnn_scan<<<NWG, 192, 0, stream>>>(cond, sig, tcg, Wc, Wf, bih, bhh,
                                       Whh16, hbuf, hc);

    wrnn_head<<<1024, 256, 0, stream>>>(hc, Wc1T, Wf1T, Wc2T, Wf2T,
                                        bc1, bf1, bc2, bf2, (float*)d_out);
}